// Round 2
// baseline (324.920 us; speedup 1.0000x reference)
//
#include <hip/hip_runtime.h>
#include <hip/hip_bf16.h>

#define B_ROWS 65536
#define XD 362

typedef __bf16 bf16;
typedef __attribute__((ext_vector_type(8))) __bf16 bf16x8;
typedef __attribute__((ext_vector_type(4))) float f32x4;
typedef __attribute__((ext_vector_type(2))) float f32x2;

#define MFMA16(A, Bf, C) __builtin_amdgcn_mfma_f32_16x16x32_bf16(A, Bf, C, 0, 0, 0)
// Block DS-op reordering by the compiler (HW keeps a wave's DS ops in order);
// VALU/SALU/MFMA/VMEM may cross.
#define ORDER() __builtin_amdgcn_sched_barrier(0x7F)

// ---- workspace layout (bytes) ----
#define OFF_W1T   0u          // [3][112][32] bf16
#define OFF_W2T   21504u      // [3][416][128] bf16 (n=400 row = bias marker)
#define OFF_W3T   340992u     // [3][112][416] bf16
#define OFF_W4T   620544u     // [3][16][128] bf16
#define OFF_CNT   632832u     // int[3]
#define OFF_PTR   633088u     // int[65536]
#define OFF_ATTC  895232u     // [3][65536][8] bf16
#define OFF_DELTA 4040960u    // [3][65536][6] f32
#define OFF_PART  8759552u    // float[MLP_GRID] per-block partials

#define MLP_GRID 1040         // >= 1026 worst-case 64-row tiles
#define WPREP_BLOCKS 624      // 624*256 = 159744 >= 3*416*128
#define SCAN_BLOCKS 2896      // 2896*256*8 float4 == 65536*362/4 exactly

// Fused: weight transpose/pack (blocks 0..623) + flat sentinel scan (rest).
__global__ __launch_bounds__(256) void k_prep(
    const float* __restrict__ W1, const float* __restrict__ b1,
    const float* __restrict__ W2, const float* __restrict__ b2,
    const float* __restrict__ W3, const float* __restrict__ b3,
    const float* __restrict__ W4, const float* __restrict__ b4,
    const float* __restrict__ x,
    bf16* __restrict__ W1t, bf16* __restrict__ W2t,
    bf16* __restrict__ W3t, bf16* __restrict__ W4t,
    int* __restrict__ cnt, int* __restrict__ ptrArr)
{
  int bx = blockIdx.x;
  if (bx >= WPREP_BLOCKS) {
    int gid = (bx - WPREP_BLOCKS) * 256 + threadIdx.x;
    const float4* x4 = (const float4*)x;
#pragma unroll
    for (int u = 0; u < 8; ++u) {
      int i = gid + u * (SCAN_BLOCKS * 256);   // exact coverage, no bounds chk
      float4 v = x4[i];
      if (v.x == 10.0f || v.y == 10.0f || v.z == 10.0f || v.w == 10.0f) {
        int flat = i * 4;
        if (v.x == 10.0f) ptrArr[(flat    ) / XD] = (flat    ) % XD;
        if (v.y == 10.0f) ptrArr[(flat + 1) / XD] = (flat + 1) % XD;
        if (v.z == 10.0f) ptrArr[(flat + 2) / XD] = (flat + 2) % XD;
        if (v.w == 10.0f) ptrArr[(flat + 3) / XD] = (flat + 3) % XD;
      }
    }
    return;
  }
  int i = bx * 256 + threadIdx.x;
  if (i == 0) { cnt[0] = 0; cnt[1] = 0; cnt[2] = 0; }
  if (i < 3*416*128) {               // W2t [n=416][k=128]
    int k = i & 127; int rn = i >> 7; int n = rn % 416; int a = rn / 416;
    float v = 0.f;
    if (n < 400) {
      if (k < 100) v = W2[(a*100 + k)*400 + n];
      else if (k == 100) v = b2[a*400 + n];
    } else if (n == 400) {
      v = (k == 100) ? 1.0f : 0.0f;  // bias-marker row: h2[*][400] = h1[*][100] = 1
    }
    W2t[i] = (bf16)v;
  }
  if (i < 3*112*416) {               // W3t [n=112][k=416]
    int k = i % 416; int rn = i / 416; int n = rn % 112; int a = rn / 112;
    float v = 0.f;
    if (n < 100) {
      if (k < 400) v = W3[(a*400 + k)*100 + n];
      else if (k == 400) v = b3[a*100 + n];
    }
    W3t[i] = (bf16)v;
  }
  if (i < 3*112*32) {                // W1t [n=112][k=32]
    int k = i & 31; int rn = i >> 5; int n = rn % 112; int a = rn / 112;
    float v = 0.f;
    if (n < 100) {
      if (k < 6) v = W1[(a*6 + k)*100 + n];
      else if (k == 6) v = b1[a*100 + n];
    }
    W1t[i] = (bf16)v;
  }
  if (i < 3*16*128) {                // W4t [n=16][k=128]
    int k = i & 127; int rn = i >> 7; int n = rn & 15; int a = rn >> 4;
    float v = 0.f;
    if (n < 6) {
      if (k < 100) v = W4[(a*100 + k)*6 + n];
      else if (k == 100) v = b4[a*6 + n];
    }
    W4t[i] = (bf16)v;
  }
}

// One thread per row: gather 6 cells from x/xn, per-wave ballot compaction
// into action-sorted arrays (3 native int atomics per wave).
__global__ __launch_bounds__(256) void k_gather2(
    const float* __restrict__ x, const float* __restrict__ xn,
    const int* __restrict__ act, const int* __restrict__ ptrArr,
    bf16* __restrict__ attC, float* __restrict__ deltaC, int* __restrict__ cnt)
{
  int row = blockIdx.x * 256 + threadIdx.x;
  int lane = threadIdx.x & 63;
  int p = ptrArr[row];
  if (p < 20 || p > 342) p = 20;   // reference guarantees 20..342
  const float* xr = x  + (size_t)row * XD;
  const float* nr = xn + (size_t)row * XD;
  int cells[6] = {0, p, p - 19, p + 19, p - 1, p + 1};
  float av[6], dv[6];
#pragma unroll
  for (int i = 0; i < 6; ++i) {
    av[i] = xr[cells[i]];
    dv[i] = nr[cells[i]] - av[i];
  }
  int a = act[row];
  unsigned long long m0 = __ballot(a == 0);
  unsigned long long m1 = __ballot(a == 1);
  unsigned long long m2 = __ballot(a == 2);
  int b0 = 0, b1 = 0, b2 = 0;
  if (lane == 0) {
    b0 = atomicAdd(&cnt[0], (int)__popcll(m0));
    b1 = atomicAdd(&cnt[1], (int)__popcll(m1));
    b2 = atomicAdd(&cnt[2], (int)__popcll(m2));
  }
  b0 = __shfl(b0, 0); b1 = __shfl(b1, 0); b2 = __shfl(b2, 0);
  unsigned long long lt = (1ull << lane) - 1ull;
  unsigned long long ma = (a == 0) ? m0 : (a == 1) ? m1 : m2;
  int base            = (a == 0) ? b0 : (a == 1) ? b1 : b2;
  int slot = base + (int)__popcll(ma & lt);
  size_t rb = (size_t)a * B_ROWS + slot;
  bf16x8 av8;
#pragma unroll
  for (int i = 0; i < 6; ++i) av8[i] = (bf16)av[i];
  av8[6] = (bf16)1.0f;   // bias marker
  av8[7] = (bf16)0.0f;
  *(bf16x8*)(attC + rb * 8) = av8;
  f32x2 d01 = {dv[0], dv[1]}, d23 = {dv[2], dv[3]}, d45 = {dv[4], dv[5]};
  *(f32x2*)(deltaC + rb * 6)     = d01;
  *(f32x2*)(deltaC + rb * 6 + 2) = d23;
  *(f32x2*)(deltaC + rb * 6 + 4) = d45;
}

// 64-row tiles, 4 waves x 16 rows each. Grid ~1026 blocks -> with
// __launch_bounds__(256,4) (VGPR<=128) 4 blocks/CU are resident:
// 16 waves/CU = 4 waves/SIMD, 2x the TLP of the previous 128-row version.
// Per-t loads are issued straight (no rotation pipeline) — wave-level
// parallelism hides the L2-hit latency instead.
__global__ __launch_bounds__(256, 4) void k_mlp(
    const bf16* __restrict__ W1t, const bf16* __restrict__ W2t,
    const bf16* __restrict__ W3t, const bf16* __restrict__ W4t,
    const bf16* __restrict__ attC, const float* __restrict__ deltaC,
    const int* __restrict__ cnt, float* __restrict__ partial)
{
  int c0 = cnt[0], c1 = cnt[1], c2 = cnt[2];
  int T0 = (c0 + 63) >> 6, T1 = (c1 + 63) >> 6, T2 = (c2 + 63) >> 6;
  int b = blockIdx.x;
  int a, tile, count;
  if (b < T0)           { a = 0; tile = b;            count = c0; }
  else if (b < T0 + T1) { a = 1; tile = b - T0;       count = c1; }
  else if (b < T0 + T1 + T2) { a = 2; tile = b - T0 - T1; count = c2; }
  else { if (threadIdx.x == 0) partial[b] = 0.f; return; }
  int start = tile << 6;

  __shared__ __align__(16) bf16 h1s[4][16][136];   // per-wave transpose scratch
  __shared__ __align__(16) bf16 tr[4][16][40];     // per-wave h2-chunk scratch
  __shared__ float s_part[4];
  int wv = threadIdx.x >> 6, lane = threadIdx.x & 63;
  int q = lane >> 4, c = lane & 15;

  const bf16* W1a = W1t + a * 112 * 32;
  const bf16* W2a = W2t + a * 416 * 128;
  const bf16* W3a = W3t + a * 112 * 416;
  const bf16* W4a = W4t + a * 16 * 128;

  // zero this wave's h1s pad cols 112..127 (read as A-frag k=96..127;
  // W2t rows there are 0, but garbage could be NaN/Inf -> NaN*0=NaN)
  for (int i = lane; i < 16 * 16; i += 64)
    h1s[wv][i >> 4][112 + (i & 15)] = (bf16)0.0f;

  // ---- L1: 6(+bias)->100, one 16-row m-tile per wave ----
  bf16x8 aAtt;
#pragma unroll
  for (int i = 0; i < 8; ++i) aAtt[i] = (bf16)0.0f;
  int slot = start + wv * 16 + c;
  if (q == 0 && slot < count)
    aAtt = *(const bf16x8*)(attC + ((size_t)a * B_ROWS + slot) * 8);
#pragma unroll
  for (int nt = 0; nt < 7; ++nt) {
    bf16x8 bw = *(const bf16x8*)(W1a + (nt * 16 + c) * 32 + q * 8);
    f32x4 C = {0.f, 0.f, 0.f, 0.f};
    C = MFMA16(aAtt, bw, C);
    int n = nt * 16 + c;
#pragma unroll
    for (int rg = 0; rg < 4; ++rg) {
      float v = (n < 100) ? (C[rg] > 0.f ? C[rg] : 0.f)
                          : (n == 100 ? 1.0f : 0.0f);
      h1s[wv][q * 4 + rg][n] = (bf16)v;
    }
  }
  ORDER();
  bf16x8 A2[4];
#pragma unroll
  for (int tt = 0; tt < 4; ++tt)
    A2[tt] = *(const bf16x8*)&h1s[wv][c][tt * 32 + q * 8];
  ORDER();

  f32x4 C3[7];
#pragma unroll
  for (int i = 0; i < 7; ++i) C3[i] = (f32x4){0.f, 0.f, 0.f, 0.f};

  // ---- L2+L3 fused, 13 uniform iterations ----
#pragma unroll 1
  for (int t = 0; t < 13; ++t) {
    // issue all fragment loads for this iteration up front
    bf16x8 w3f[7];
#pragma unroll
    for (int nt3 = 0; nt3 < 7; ++nt3)
      w3f[nt3] = *(const bf16x8*)(W3a + (nt3 * 16 + c) * 416 + t * 32 + q * 8);
    bf16x8 b2f[2][4];
#pragma unroll
    for (int half = 0; half < 2; ++half)
#pragma unroll
      for (int tt = 0; tt < 4; ++tt)
        b2f[half][tt] = *(const bf16x8*)(W2a + ((2 * t + half) * 16 + c) * 128 + tt * 32 + q * 8);
    __builtin_amdgcn_sched_barrier(0);    // keep loads clustered above compute

    // L2: h2 chunk (32 cols) for this wave's m-tile
#pragma unroll
    for (int half = 0; half < 2; ++half) {
      f32x4 C = {0.f, 0.f, 0.f, 0.f};
#pragma unroll
      for (int tt = 0; tt < 4; ++tt)
        C = MFMA16(A2[tt], b2f[half][tt], C);
#pragma unroll
      for (int rg = 0; rg < 4; ++rg) {
        float v = C[rg] > 0.f ? C[rg] : 0.f;
        tr[wv][q * 4 + rg][half * 16 + c] = (bf16)v;
      }
    }
    ORDER();
    bf16x8 A3 = *(const bf16x8*)&tr[wv][c][q * 8];
#pragma unroll
    for (int nt3 = 0; nt3 < 7; ++nt3)
      C3[nt3] = MFMA16(A3, w3f[nt3], C3[nt3]);
    ORDER();   // before next t overwrites tr
  }

  // ---- L4: 100(+bias)->6 + MSE ----
  bf16x8 b4f[4];
#pragma unroll
  for (int tt = 0; tt < 4; ++tt)
    b4f[tt] = *(const bf16x8*)(W4a + c * 128 + tt * 32 + q * 8);
  float sq = 0.f;
#pragma unroll
  for (int nt3 = 0; nt3 < 7; ++nt3) {
    int n = nt3 * 16 + c;
#pragma unroll
    for (int rg = 0; rg < 4; ++rg) {
      float v = (n < 100) ? (C3[nt3][rg] > 0.f ? C3[nt3][rg] : 0.f)
                          : (n == 100 ? 1.0f : 0.0f);
      h1s[wv][q * 4 + rg][n] = (bf16)v;
    }
  }
  ORDER();
  f32x4 C4 = {0.f, 0.f, 0.f, 0.f};
#pragma unroll
  for (int tt = 0; tt < 4; ++tt) {
    bf16x8 A4 = *(const bf16x8*)&h1s[wv][c][tt * 32 + q * 8];
    C4 = MFMA16(A4, b4f[tt], C4);
  }
  ORDER();
  if (c < 6) {
#pragma unroll
    for (int rg = 0; rg < 4; ++rg) {
      int slot2 = start + wv * 16 + q * 4 + rg;
      if (slot2 < count) {
        float d = deltaC[((size_t)a * B_ROWS + slot2) * 6 + c];
        float e = C4[rg] - d;
        sq += e * e;
      }
    }
  }
#pragma unroll
  for (int off = 32; off; off >>= 1) sq += __shfl_xor(sq, off);
  if (lane == 0) s_part[wv] = sq;
  __syncthreads();
  if (threadIdx.x == 0)
    partial[b] = s_part[0] + s_part[1] + s_part[2] + s_part[3];
}

// One-block tree reduction over per-block partials.
__global__ __launch_bounds__(256) void k_final(
    const float* __restrict__ partial, float* __restrict__ out)
{
  __shared__ float s[4];
  int t = threadIdx.x, lane = t & 63, wv = t >> 6;
  float sum = 0.f;
  for (int i = t; i < MLP_GRID; i += 256) sum += partial[i];
#pragma unroll
  for (int off = 32; off; off >>= 1) sum += __shfl_xor(sum, off);
  if (lane == 0) s[wv] = sum;
  __syncthreads();
  if (t == 0) {
    double tot = (double)s[0] + s[1] + s[2] + s[3];
    out[0] = (float)(tot / (double)(B_ROWS * 6));
  }
}

extern "C" void kernel_launch(void* const* d_in, const int* in_sizes, int n_in,
                              void* d_out, int out_size, void* d_ws, size_t ws_size,
                              hipStream_t stream)
{
  const float* x  = (const float*)d_in[0];
  const float* xn = (const float*)d_in[1];
  const int*  act = (const int*)d_in[2];
  const float* W1 = (const float*)d_in[3];
  const float* b1 = (const float*)d_in[4];
  const float* W2 = (const float*)d_in[5];
  const float* b2 = (const float*)d_in[6];
  const float* W3 = (const float*)d_in[7];
  const float* b3 = (const float*)d_in[8];
  const float* W4 = (const float*)d_in[9];
  const float* b4 = (const float*)d_in[10];

  char* ws = (char*)d_ws;
  bf16*   W1t    = (bf16*)(ws + OFF_W1T);
  bf16*   W2t    = (bf16*)(ws + OFF_W2T);
  bf16*   W3t    = (bf16*)(ws + OFF_W3T);
  bf16*   W4t    = (bf16*)(ws + OFF_W4T);
  int*    cnt    = (int*)(ws + OFF_CNT);
  int*    ptrArr = (int*)(ws + OFF_PTR);
  bf16*   attC   = (bf16*)(ws + OFF_ATTC);
  float*  deltaC = (float*)(ws + OFF_DELTA);
  float*  part   = (float*)(ws + OFF_PART);

  k_prep<<<dim3(WPREP_BLOCKS + SCAN_BLOCKS), dim3(256), 0, stream>>>(
      W1, b1, W2, b2, W3, b3, W4, b4, x, W1t, W2t, W3t, W4t, cnt, ptrArr);
  k_gather2<<<dim3(B_ROWS / 256), dim3(256), 0, stream>>>(x, xn, act, ptrArr,
                                                          attC, deltaC, cnt);
  k_mlp<<<dim3(MLP_GRID), dim3(256), 0, stream>>>(W1t, W2t, W3t, W4t,
                                                  attC, deltaC, cnt, part);
  k_final<<<dim3(1), dim3(256), 0, stream>>>(part, (float*)d_out);
}

// Round 3
// 272.947 us; speedup vs baseline: 1.1904x; 1.1904x over previous
//
#include <hip/hip_runtime.h>
#include <hip/hip_bf16.h>

#define B_ROWS 65536
#define XD 362

typedef __bf16 bf16;
typedef __attribute__((ext_vector_type(8))) __bf16 bf16x8;
typedef __attribute__((ext_vector_type(4))) float f32x4;
typedef __attribute__((ext_vector_type(2))) float f32x2;

#define MFMA16(A, Bf, C) __builtin_amdgcn_mfma_f32_16x16x32_bf16(A, Bf, C, 0, 0, 0)
// Block DS-op reordering by the compiler (HW keeps a wave's DS ops in order).
#define ORDER() __builtin_amdgcn_sched_barrier(0x7F)

// ---- workspace layout (bytes) ----
#define OFF_W1T   0u          // [3][112][32] bf16
#define OFF_W2T   21504u      // [3][416][128] bf16, granule-swizzled (see below)
#define OFF_W3T   340992u     // [3][13][112][32] bf16, granule-swizzled
#define OFF_W4T   620544u     // [3][16][128] bf16
#define OFF_CNT   632832u     // int[3]
#define OFF_PTR   633088u     // int[65536]
#define OFF_ATTC  895232u     // [3][65536][8] bf16
#define OFF_DELTA 4040960u    // [3][65536][6] f32
#define OFF_PART  8759552u    // float[MLP_GRID] per-block partials

#define MLP_GRID 520          // >= 514 worst-case 128-row tiles
#define WPREP_BLOCKS 624      // 624*256 = 159744 >= 3*416*128
#define SCAN_BLOCKS 2896      // 2896*256*8 float4 == 65536*362/4 exactly

// W2t swizzle: element [a][n][g*8+e] stores logical W2^T[n][k=(g^(n&7))*8+e].
//   (g in 0..15; XOR makes ds_read_b128 of a 16-row column slice bank-optimal.)
// W3t swizzle: chunked [a][t][n][g*8+e] stores logical W3^T[n][k=t*32+(g^(n&3))*8+e].
//   (g in 0..3; chunk t is contiguous 7168 B so global_load_lds can stage it linearly.)

// Fused: weight transpose/pack (blocks 0..623) + flat sentinel scan (rest).
__global__ __launch_bounds__(256) void k_prep(
    const float* __restrict__ W1, const float* __restrict__ b1,
    const float* __restrict__ W2, const float* __restrict__ b2,
    const float* __restrict__ W3, const float* __restrict__ b3,
    const float* __restrict__ W4, const float* __restrict__ b4,
    const float* __restrict__ x,
    bf16* __restrict__ W1t, bf16* __restrict__ W2t,
    bf16* __restrict__ W3t, bf16* __restrict__ W4t,
    int* __restrict__ cnt, int* __restrict__ ptrArr)
{
  int bx = blockIdx.x;
  if (bx >= WPREP_BLOCKS) {
    int gid = (bx - WPREP_BLOCKS) * 256 + threadIdx.x;
    const float4* x4 = (const float4*)x;
#pragma unroll
    for (int u = 0; u < 8; ++u) {
      int i = gid + u * (SCAN_BLOCKS * 256);   // exact coverage, no bounds chk
      float4 v = x4[i];
      if (v.x == 10.0f || v.y == 10.0f || v.z == 10.0f || v.w == 10.0f) {
        int flat = i * 4;
        if (v.x == 10.0f) ptrArr[(flat    ) / XD] = (flat    ) % XD;
        if (v.y == 10.0f) ptrArr[(flat + 1) / XD] = (flat + 1) % XD;
        if (v.z == 10.0f) ptrArr[(flat + 2) / XD] = (flat + 2) % XD;
        if (v.w == 10.0f) ptrArr[(flat + 3) / XD] = (flat + 3) % XD;
      }
    }
    return;
  }
  int i = bx * 256 + threadIdx.x;
  if (i == 0) { cnt[0] = 0; cnt[1] = 0; cnt[2] = 0; }
  if (i < 3*416*128) {               // W2t [n=416][128], granule-swizzled
    int e = i & 7; int g = (i >> 3) & 15;
    int rn = i >> 7; int n = rn % 416; int a = rn / 416;
    int k = ((g ^ (n & 7)) << 3) | e;
    float v = 0.f;
    if (n < 400) {
      if (k < 100) v = W2[(a*100 + k)*400 + n];
      else if (k == 100) v = b2[a*400 + n];
    } else if (n == 400) {
      v = (k == 100) ? 1.0f : 0.0f;  // bias-marker row: h2[*][400] = h1[*][100] = 1
    }
    W2t[i] = (bf16)v;
  }
  if (i < 3*13*112*32) {             // W3t [13 chunks][n=112][32], granule-swizzled
    int e = i & 7; int g = (i >> 3) & 3;
    int n = (i >> 5) % 112; int tc = ((i >> 5) / 112) % 13; int a = i / (13*112*32);
    int k = tc * 32 + ((g ^ (n & 3)) << 3) + e;
    float v = 0.f;
    if (n < 100) {
      if (k < 400) v = W3[(a*400 + k)*100 + n];
      else if (k == 400) v = b3[a*100 + n];
    }
    W3t[i] = (bf16)v;
  }
  if (i < 3*112*32) {                // W1t [n=112][k=32]
    int k = i & 31; int rn = i >> 5; int n = rn % 112; int a = rn / 112;
    float v = 0.f;
    if (n < 100) {
      if (k < 6) v = W1[(a*6 + k)*100 + n];
      else if (k == 6) v = b1[a*100 + n];
    }
    W1t[i] = (bf16)v;
  }
  if (i < 3*16*128) {                // W4t [n=16][k=128]
    int k = i & 127; int rn = i >> 7; int n = rn & 15; int a = rn >> 4;
    float v = 0.f;
    if (n < 6) {
      if (k < 100) v = W4[(a*100 + k)*6 + n];
      else if (k == 100) v = b4[a*6 + n];
    }
    W4t[i] = (bf16)v;
  }
}

// One thread per row: gather 6 cells from x/xn, per-wave ballot compaction
// into action-sorted arrays (3 native int atomics per wave).
__global__ __launch_bounds__(256) void k_gather2(
    const float* __restrict__ x, const float* __restrict__ xn,
    const int* __restrict__ act, const int* __restrict__ ptrArr,
    bf16* __restrict__ attC, float* __restrict__ deltaC, int* __restrict__ cnt)
{
  int row = blockIdx.x * 256 + threadIdx.x;
  int lane = threadIdx.x & 63;
  int p = ptrArr[row];
  if (p < 20 || p > 342) p = 20;   // reference guarantees 20..342
  const float* xr = x  + (size_t)row * XD;
  const float* nr = xn + (size_t)row * XD;
  int cells[6] = {0, p, p - 19, p + 19, p - 1, p + 1};
  float av[6], dv[6];
#pragma unroll
  for (int i = 0; i < 6; ++i) {
    av[i] = xr[cells[i]];
    dv[i] = nr[cells[i]] - av[i];
  }
  int a = act[row];
  unsigned long long m0 = __ballot(a == 0);
  unsigned long long m1 = __ballot(a == 1);
  unsigned long long m2 = __ballot(a == 2);
  int b0 = 0, b1 = 0, b2 = 0;
  if (lane == 0) {
    b0 = atomicAdd(&cnt[0], (int)__popcll(m0));
    b1 = atomicAdd(&cnt[1], (int)__popcll(m1));
    b2 = atomicAdd(&cnt[2], (int)__popcll(m2));
  }
  b0 = __shfl(b0, 0); b1 = __shfl(b1, 0); b2 = __shfl(b2, 0);
  unsigned long long lt = (1ull << lane) - 1ull;
  unsigned long long ma = (a == 0) ? m0 : (a == 1) ? m1 : m2;
  int base            = (a == 0) ? b0 : (a == 1) ? b1 : b2;
  int slot = base + (int)__popcll(ma & lt);
  size_t rb = (size_t)a * B_ROWS + slot;
  bf16x8 av8;
#pragma unroll
  for (int i = 0; i < 6; ++i) av8[i] = (bf16)av[i];
  av8[6] = (bf16)1.0f;   // bias marker
  av8[7] = (bf16)0.0f;
  *(bf16x8*)(attC + rb * 8) = av8;
  f32x2 d01 = {dv[0], dv[1]}, d23 = {dv[2], dv[3]}, d45 = {dv[4], dv[5]};
  *(f32x2*)(deltaC + rb * 6)     = d01;
  *(f32x2*)(deltaC + rb * 6 + 2) = d23;
  *(f32x2*)(deltaC + rb * 6 + 4) = d45;
}

// 128-row tiles, 4 waves x 32 rows. Per t-iteration the block stages the
// 15 KB weight chunk (W2: 8 KB contiguous, W3: 7 KB contiguous) into LDS
// ONCE via global_load_lds width-16 (15 wave-loads/block instead of 60),
// double-buffered with a single __syncthreads per iteration (T3 2-phase).
// Waves read fragments via ds_read_b128 from the swizzled LDS images --
// no global weight traffic inside the loop, killing the same-line L1/L2
// contention that round-1/2 profiles showed (all pipes <11% busy, ~87%
// stall, time scaling with redundant load count).
__global__ __launch_bounds__(256, 2) void k_mlp(
    const bf16* __restrict__ W1t, const bf16* __restrict__ W2t,
    const bf16* __restrict__ W3t, const bf16* __restrict__ W4t,
    const bf16* __restrict__ attC, const float* __restrict__ deltaC,
    const int* __restrict__ cnt, float* __restrict__ partial)
{
  int c0 = cnt[0], c1 = cnt[1], c2 = cnt[2];
  int T0 = (c0 + 127) >> 7, T1 = (c1 + 127) >> 7, T2 = (c2 + 127) >> 7;
  int b = blockIdx.x;
  int a, tile, count;
  if (b < T0)           { a = 0; tile = b;            count = c0; }
  else if (b < T0 + T1) { a = 1; tile = b - T0;       count = c1; }
  else if (b < T0 + T1 + T2) { a = 2; tile = b - T0 - T1; count = c2; }
  else { if (threadIdx.x == 0) partial[b] = 0.f; return; }
  int start = tile << 7;

  __shared__ __align__(16) bf16 bufW2[2][32][128];   // 2 x 8 KB chunk
  __shared__ __align__(16) bf16 bufW3[2][112][32];   // 2 x 7 KB chunk
  __shared__ __align__(16) bf16 h1s[4][16][136];     // per-wave transpose scratch
  __shared__ __align__(16) bf16 tr[4][2][16][56];    // per-wave,per-mtile chunk
  __shared__ float s_part[4];
  int wv = threadIdx.x >> 6, lane = threadIdx.x & 63;
  int q = lane >> 4, c = lane & 15;
  int cx7 = c & 7, cx3 = c & 3;

  const bf16* W1a = W1t + a * 112 * 32;
  const bf16* W2a = W2t + a * 416 * 128;
  const bf16* W3a = W3t + a * 13 * 112 * 32;
  const bf16* W4a = W4t + a * 16 * 128;

  // cooperative stage of chunk tn into buf[tn&1]: 15 x 1KB wave-loads,
  // linear LDS dest (global_load_lds constraint), swizzle lives in W*t layout
  auto stage = [&](int tn) {
    const char* s2 = (const char*)W2a + tn * 8192;
    const char* s3 = (const char*)W3a + tn * 7168;
    char* d2 = (char*)&bufW2[tn & 1][0][0];
    char* d3 = (char*)&bufW3[tn & 1][0][0];
#pragma unroll
    for (int id = wv; id < 15; id += 4) {
      const char* src = (id < 8) ? s2 + id * 1024 + lane * 16
                                 : s3 + (id - 8) * 1024 + lane * 16;
      char* dst = (id < 8) ? d2 + id * 1024 : d3 + (id - 8) * 1024;
      __builtin_amdgcn_global_load_lds(
          (const __attribute__((address_space(1))) unsigned int*)src,
          (__attribute__((address_space(3))) unsigned int*)dst, 16, 0, 0);
    }
  };

  stage(0);   // prologue stage overlaps the L1 phase below

  // zero this wave's h1s pad cols 112..127 (read as A-frag k=96..127)
  for (int i = lane; i < 16 * 16; i += 64)
    h1s[wv][i >> 4][112 + (i & 15)] = (bf16)0.0f;

  // ---- L1: 6(+bias)->100, per m-tile, A2 frags kept in registers ----
  bf16x8 A2[2][4];
#pragma unroll
  for (int mi = 0; mi < 2; ++mi) {
    bf16x8 aAtt;
#pragma unroll
    for (int i = 0; i < 8; ++i) aAtt[i] = (bf16)0.0f;
    int slot = start + wv * 32 + mi * 16 + c;
    if (q == 0 && slot < count)
      aAtt = *(const bf16x8*)(attC + ((size_t)a * B_ROWS + slot) * 8);
#pragma unroll
    for (int nt = 0; nt < 7; ++nt) {
      bf16x8 bw = *(const bf16x8*)(W1a + (nt * 16 + c) * 32 + q * 8);
      f32x4 C = {0.f, 0.f, 0.f, 0.f};
      C = MFMA16(aAtt, bw, C);
      int n = nt * 16 + c;
#pragma unroll
      for (int rg = 0; rg < 4; ++rg) {
        float v = (n < 100) ? (C[rg] > 0.f ? C[rg] : 0.f)
                            : (n == 100 ? 1.0f : 0.0f);
        h1s[wv][q * 4 + rg][n] = (bf16)v;
      }
    }
    ORDER();
#pragma unroll
    for (int tt = 0; tt < 4; ++tt)
      A2[mi][tt] = *(const bf16x8*)&h1s[wv][c][tt * 32 + q * 8];
    ORDER();   // before next mi overwrites h1s
  }

  f32x4 C3[2][7];
#pragma unroll
  for (int mi = 0; mi < 2; ++mi)
#pragma unroll
    for (int i = 0; i < 7; ++i) C3[mi][i] = (f32x4){0.f, 0.f, 0.f, 0.f};

  __syncthreads();   // stage(0) landed (vmcnt0) + all waves ready

  // ---- L2+L3 fused, 13 iterations, LDS double-buffered weights ----
#pragma unroll 1
  for (int t = 0; t < 13; ++t) {
    if (t < 12) stage(t + 1);           // prefetch next chunk into buf^1
    __builtin_amdgcn_sched_barrier(0);  // keep stage issue above compute

    const bf16* cw2 = &bufW2[t & 1][0][0];
    const bf16* cw3 = &bufW3[t & 1][0][0];
    // fragment reads from swizzled LDS images (8 lanes/bank = b128-optimal)
    bf16x8 w3f[7];
#pragma unroll
    for (int nt3 = 0; nt3 < 7; ++nt3)
      w3f[nt3] = *(const bf16x8*)(cw3 + (nt3 * 16 + c) * 32 + ((q ^ cx3) << 3));
    bf16x8 b2f[2][4];
#pragma unroll
    for (int half = 0; half < 2; ++half)
#pragma unroll
      for (int tt = 0; tt < 4; ++tt)
        b2f[half][tt] = *(const bf16x8*)(cw2 + (half * 16 + c) * 128 +
                                         ((((tt << 2) + q) ^ cx7) << 3));

    // L2: h2 chunk (32 cols) for both m-tiles
#pragma unroll
    for (int mi = 0; mi < 2; ++mi)
#pragma unroll
      for (int half = 0; half < 2; ++half) {
        f32x4 C = {0.f, 0.f, 0.f, 0.f};
#pragma unroll
        for (int tt = 0; tt < 4; ++tt)
          C = MFMA16(A2[mi][tt], b2f[half][tt], C);
#pragma unroll
        for (int rg = 0; rg < 4; ++rg) {
          float v = C[rg] > 0.f ? C[rg] : 0.f;
          tr[wv][mi][q * 4 + rg][half * 16 + c] = (bf16)v;
        }
      }
    ORDER();
    bf16x8 A3a = *(const bf16x8*)&tr[wv][0][c][q * 8];
    bf16x8 A3b = *(const bf16x8*)&tr[wv][1][c][q * 8];
#pragma unroll
    for (int nt3 = 0; nt3 < 7; ++nt3) {
      C3[0][nt3] = MFMA16(A3a, w3f[nt3], C3[0][nt3]);
      C3[1][nt3] = MFMA16(A3b, w3f[nt3], C3[1][nt3]);
    }
    ORDER();
    __syncthreads();   // all waves done with buf[t&1]; staged loads drained
  }

  // ---- L4: 100(+bias)->6 + MSE, per m-tile (h1s serial reuse) ----
  bf16x8 b4f[4];
#pragma unroll
  for (int tt = 0; tt < 4; ++tt)
    b4f[tt] = *(const bf16x8*)(W4a + c * 128 + tt * 32 + q * 8);
  float sq = 0.f;
#pragma unroll
  for (int mi = 0; mi < 2; ++mi) {
#pragma unroll
    for (int nt3 = 0; nt3 < 7; ++nt3) {
      int n = nt3 * 16 + c;
#pragma unroll
      for (int rg = 0; rg < 4; ++rg) {
        float v = (n < 100) ? (C3[mi][nt3][rg] > 0.f ? C3[mi][nt3][rg] : 0.f)
                            : (n == 100 ? 1.0f : 0.0f);
        h1s[wv][q * 4 + rg][n] = (bf16)v;
      }
    }
    ORDER();
    f32x4 C4 = {0.f, 0.f, 0.f, 0.f};
#pragma unroll
    for (int tt = 0; tt < 4; ++tt) {
      bf16x8 A4 = *(const bf16x8*)&h1s[wv][c][tt * 32 + q * 8];
      C4 = MFMA16(A4, b4f[tt], C4);
    }
    ORDER();   // before next mi overwrites h1s
    if (c < 6) {
#pragma unroll
      for (int rg = 0; rg < 4; ++rg) {
        int slot = start + wv * 32 + mi * 16 + q * 4 + rg;
        if (slot < count) {
          float d = deltaC[((size_t)a * B_ROWS + slot) * 6 + c];
          float e = C4[rg] - d;
          sq += e * e;
        }
      }
    }
  }
#pragma unroll
  for (int off = 32; off; off >>= 1) sq += __shfl_xor(sq, off);
  if (lane == 0) s_part[wv] = sq;
  __syncthreads();
  if (threadIdx.x == 0)
    partial[b] = s_part[0] + s_part[1] + s_part[2] + s_part[3];
}

// One-block tree reduction over per-block partials.
__global__ __launch_bounds__(256) void k_final(
    const float* __restrict__ partial, float* __restrict__ out)
{
  __shared__ float s[4];
  int t = threadIdx.x, lane = t & 63, wv = t >> 6;
  float sum = 0.f;
  for (int i = t; i < MLP_GRID; i += 256) sum += partial[i];
#pragma unroll
  for (int off = 32; off; off >>= 1) sum += __shfl_xor(sum, off);
  if (lane == 0) s[wv] = sum;
  __syncthreads();
  if (t == 0) {
    double tot = (double)s[0] + s[1] + s[2] + s[3];
    out[0] = (float)(tot / (double)(B_ROWS * 6));
  }
}

extern "C" void kernel_launch(void* const* d_in, const int* in_sizes, int n_in,
                              void* d_out, int out_size, void* d_ws, size_t ws_size,
                              hipStream_t stream)
{
  const float* x  = (const float*)d_in[0];
  const float* xn = (const float*)d_in[1];
  const int*  act = (const int*)d_in[2];
  const float* W1 = (const float*)d_in[3];
  const float* b1 = (const float*)d_in[4];
  const float* W2 = (const float*)d_in[5];
  const float* b2 = (const float*)d_in[6];
  const float* W3 = (const float*)d_in[7];
  const float* b3 = (const float*)d_in[8];
  const float* W4 = (const float*)d_in[9];
  const float* b4 = (const float*)d_in[10];

  char* ws = (char*)d_ws;
  bf16*   W1t    = (bf16*)(ws + OFF_W1T);
  bf16*   W2t    = (bf16*)(ws + OFF_W2T);
  bf16*   W3t    = (bf16*)(ws + OFF_W3T);
  bf16*   W4t    = (bf16*)(ws + OFF_W4T);
  int*    cnt    = (int*)(ws + OFF_CNT);
  int*    ptrArr = (int*)(ws + OFF_PTR);
  bf16*   attC   = (bf16*)(ws + OFF_ATTC);
  float*  deltaC = (float*)(ws + OFF_DELTA);
  float*  part   = (float*)(ws + OFF_PART);

  k_prep<<<dim3(WPREP_BLOCKS + SCAN_BLOCKS), dim3(256), 0, stream>>>(
      W1, b1, W2, b2, W3, b3, W4, b4, x, W1t, W2t, W3t, W4t, cnt, ptrArr);
  k_gather2<<<dim3(B_ROWS / 256), dim3(256), 0, stream>>>(x, xn, act, ptrArr,
                                                          attC, deltaC, cnt);
  k_mlp<<<dim3(MLP_GRID), dim3(256), 0, stream>>>(W1t, W2t, W3t, W4t,
                                                  attC, deltaC, cnt, part);
  k_final<<<dim3(1), dim3(256), 0, stream>>>(part, (float*)d_out);
}

// Round 4
// 272.731 us; speedup vs baseline: 1.1914x; 1.0008x over previous
//
#include <hip/hip_runtime.h>
#include <hip/hip_bf16.h>

#define B_ROWS 65536
#define XD 362

typedef __bf16 bf16;
typedef __attribute__((ext_vector_type(8))) __bf16 bf16x8;
typedef __attribute__((ext_vector_type(4))) float f32x4;
typedef __attribute__((ext_vector_type(2))) float f32x2;

#define MFMA16(A, Bf, C) __builtin_amdgcn_mfma_f32_16x16x32_bf16(A, Bf, C, 0, 0, 0)
// Block DS-op reordering by the compiler (HW keeps a wave's DS ops in order).
#define ORDER() __builtin_amdgcn_sched_barrier(0x7F)

// ---- workspace layout (bytes) ----
#define OFF_W1T   0u          // [3][112][32] bf16
#define OFF_W2T   21504u      // [3][416][128] bf16, granule-swizzled (see below)
#define OFF_W3T   340992u     // [3][13][112][32] bf16, granule-swizzled
#define OFF_W4T   620544u     // [3][16][128] bf16
#define OFF_CNT   632832u     // int[3]
#define OFF_PTR   633088u     // int[65536]
#define OFF_ATTC  895232u     // [3][65536][8] bf16
#define OFF_DELTA 4040960u    // [3][65536][6] f32
#define OFF_PART  8759552u    // float[MLP_GRID] per-block partials

#define MLP_GRID 520          // >= 514 worst-case 128-row tiles
#define WPREP_BLOCKS 624      // 624*256 = 159744 >= 3*416*128
#define SCAN_BLOCKS 2896      // 2896*256*8 float4 == 65536*362/4 exactly

// W2t swizzle: element [a][n][g*8+e] stores logical W2^T[n][k=(g^(n&7))*8+e].
// W3t swizzle: chunked [a][t][n][g*8+e] stores logical W3^T[n][k=t*32+(g^(n&3))*8+e].

// Fused: weight transpose/pack (blocks 0..623) + flat sentinel scan (rest).
__global__ __launch_bounds__(256) void k_prep(
    const float* __restrict__ W1, const float* __restrict__ b1,
    const float* __restrict__ W2, const float* __restrict__ b2,
    const float* __restrict__ W3, const float* __restrict__ b3,
    const float* __restrict__ W4, const float* __restrict__ b4,
    const float* __restrict__ x,
    bf16* __restrict__ W1t, bf16* __restrict__ W2t,
    bf16* __restrict__ W3t, bf16* __restrict__ W4t,
    int* __restrict__ cnt, int* __restrict__ ptrArr)
{
  int bx = blockIdx.x;
  if (bx >= WPREP_BLOCKS) {
    int gid = (bx - WPREP_BLOCKS) * 256 + threadIdx.x;
    const float4* x4 = (const float4*)x;
#pragma unroll
    for (int u = 0; u < 8; ++u) {
      int i = gid + u * (SCAN_BLOCKS * 256);   // exact coverage, no bounds chk
      float4 v = x4[i];
      if (v.x == 10.0f || v.y == 10.0f || v.z == 10.0f || v.w == 10.0f) {
        int flat = i * 4;
        if (v.x == 10.0f) ptrArr[(flat    ) / XD] = (flat    ) % XD;
        if (v.y == 10.0f) ptrArr[(flat + 1) / XD] = (flat + 1) % XD;
        if (v.z == 10.0f) ptrArr[(flat + 2) / XD] = (flat + 2) % XD;
        if (v.w == 10.0f) ptrArr[(flat + 3) / XD] = (flat + 3) % XD;
      }
    }
    return;
  }
  int i = bx * 256 + threadIdx.x;
  if (i == 0) { cnt[0] = 0; cnt[1] = 0; cnt[2] = 0; }
  if (i < 3*416*128) {               // W2t [n=416][128], granule-swizzled
    int e = i & 7; int g = (i >> 3) & 15;
    int rn = i >> 7; int n = rn % 416; int a = rn / 416;
    int k = ((g ^ (n & 7)) << 3) | e;
    float v = 0.f;
    if (n < 400) {
      if (k < 100) v = W2[(a*100 + k)*400 + n];
      else if (k == 100) v = b2[a*400 + n];
    } else if (n == 400) {
      v = (k == 100) ? 1.0f : 0.0f;  // bias-marker row: h2[*][400] = h1[*][100] = 1
    }
    W2t[i] = (bf16)v;
  }
  if (i < 3*13*112*32) {             // W3t [13 chunks][n=112][32], granule-swizzled
    int e = i & 7; int g = (i >> 3) & 3;
    int n = (i >> 5) % 112; int tc = ((i >> 5) / 112) % 13; int a = i / (13*112*32);
    int k = tc * 32 + ((g ^ (n & 3)) << 3) + e;
    float v = 0.f;
    if (n < 100) {
      if (k < 400) v = W3[(a*400 + k)*100 + n];
      else if (k == 400) v = b3[a*100 + n];
    }
    W3t[i] = (bf16)v;
  }
  if (i < 3*112*32) {                // W1t [n=112][k=32]
    int k = i & 31; int rn = i >> 5; int n = rn % 112; int a = rn / 112;
    float v = 0.f;
    if (n < 100) {
      if (k < 6) v = W1[(a*6 + k)*100 + n];
      else if (k == 6) v = b1[a*100 + n];
    }
    W1t[i] = (bf16)v;
  }
  if (i < 3*16*128) {                // W4t [n=16][k=128]
    int k = i & 127; int rn = i >> 7; int n = rn & 15; int a = rn >> 4;
    float v = 0.f;
    if (n < 6) {
      if (k < 100) v = W4[(a*100 + k)*6 + n];
      else if (k == 100) v = b4[a*6 + n];
    }
    W4t[i] = (bf16)v;
  }
}

// One thread per row: gather 6 cells from x/xn, per-wave ballot compaction
// into action-sorted arrays (3 native int atomics per wave).
__global__ __launch_bounds__(256) void k_gather2(
    const float* __restrict__ x, const float* __restrict__ xn,
    const int* __restrict__ act, const int* __restrict__ ptrArr,
    bf16* __restrict__ attC, float* __restrict__ deltaC, int* __restrict__ cnt)
{
  int row = blockIdx.x * 256 + threadIdx.x;
  int lane = threadIdx.x & 63;
  int p = ptrArr[row];
  if (p < 20 || p > 342) p = 20;   // reference guarantees 20..342
  const float* xr = x  + (size_t)row * XD;
  const float* nr = xn + (size_t)row * XD;
  int cells[6] = {0, p, p - 19, p + 19, p - 1, p + 1};
  float av[6], dv[6];
#pragma unroll
  for (int i = 0; i < 6; ++i) {
    av[i] = xr[cells[i]];
    dv[i] = nr[cells[i]] - av[i];
  }
  int a = act[row];
  unsigned long long m0 = __ballot(a == 0);
  unsigned long long m1 = __ballot(a == 1);
  unsigned long long m2 = __ballot(a == 2);
  int b0 = 0, b1 = 0, b2 = 0;
  if (lane == 0) {
    b0 = atomicAdd(&cnt[0], (int)__popcll(m0));
    b1 = atomicAdd(&cnt[1], (int)__popcll(m1));
    b2 = atomicAdd(&cnt[2], (int)__popcll(m2));
  }
  b0 = __shfl(b0, 0); b1 = __shfl(b1, 0); b2 = __shfl(b2, 0);
  unsigned long long lt = (1ull << lane) - 1ull;
  unsigned long long ma = (a == 0) ? m0 : (a == 1) ? m1 : m2;
  int base            = (a == 0) ? b0 : (a == 1) ? b1 : b2;
  int slot = base + (int)__popcll(ma & lt);
  size_t rb = (size_t)a * B_ROWS + slot;
  bf16x8 av8;
#pragma unroll
  for (int i = 0; i < 6; ++i) av8[i] = (bf16)av[i];
  av8[6] = (bf16)1.0f;   // bias marker
  av8[7] = (bf16)0.0f;
  *(bf16x8*)(attC + rb * 8) = av8;
  f32x2 d01 = {dv[0], dv[1]}, d23 = {dv[2], dv[3]}, d45 = {dv[4], dv[5]};
  *(f32x2*)(deltaC + rb * 6)     = d01;
  *(f32x2*)(deltaC + rb * 6 + 2) = d23;
  *(f32x2*)(deltaC + rb * 6 + 4) = d45;
}

// 128-row tiles, 4 waves x 32 rows. Weight chunks staged to LDS via
// global_load_lds, now TRIPLE-buffered with counted-vmcnt barriers (T3/T4):
// each iteration issues stage(t+1) (exactly 4 loads/wave), then waits
// vmcnt(4) (stage(t) landed, prefetch stays in flight), one raw s_barrier,
// computes from slot t%3, and drains lgkmcnt before the next barrier.
// 3 slots + lgkmcnt(0)-before-barrier closes the WAR race (a wave passes
// barrier t-1 only after all waves completed their slot-(t+1)%3 ds_reads).
// This removes the __syncthreads vmcnt(0) drain that serialized every
// iteration on the full global->LDS round trip.
__global__ __launch_bounds__(256, 2) void k_mlp(
    const bf16* __restrict__ W1t, const bf16* __restrict__ W2t,
    const bf16* __restrict__ W3t, const bf16* __restrict__ W4t,
    const bf16* __restrict__ attC, const float* __restrict__ deltaC,
    const int* __restrict__ cnt, float* __restrict__ partial)
{
  int c0 = cnt[0], c1 = cnt[1], c2 = cnt[2];
  int T0 = (c0 + 127) >> 7, T1 = (c1 + 127) >> 7, T2 = (c2 + 127) >> 7;
  int b = blockIdx.x;
  int a, tile, count;
  if (b < T0)           { a = 0; tile = b;            count = c0; }
  else if (b < T0 + T1) { a = 1; tile = b - T0;       count = c1; }
  else if (b < T0 + T1 + T2) { a = 2; tile = b - T0 - T1; count = c2; }
  else { if (threadIdx.x == 0) partial[b] = 0.f; return; }
  int start = tile << 7;

  __shared__ __align__(16) bf16 bufW2[3][32][128];   // 3 x 8 KB chunk
  __shared__ __align__(16) bf16 bufW3[3][112][32];   // 3 x 7 KB chunk
  __shared__ __align__(16) bf16 dummyLds[512];       // 1 KB stage filler
  __shared__ __align__(16) bf16 h1s[4][16][136];     // per-wave transpose scratch
  __shared__ __align__(16) bf16 tr[4][2][16][56];    // per-wave,per-mtile chunk
  __shared__ float s_part[4];
  int wv = threadIdx.x >> 6, lane = threadIdx.x & 63;
  int q = lane >> 4, c = lane & 15;
  int cx7 = c & 7, cx3 = c & 3;

  const bf16* W1a = W1t + a * 112 * 32;
  const bf16* W2a = W2t + a * 416 * 128;
  const bf16* W3a = W3t + a * 13 * 112 * 32;
  const bf16* W4a = W4t + a * 16 * 128;

  // cooperative stage of chunk tn into slot tn%3: exactly 16 x 1KB loads
  // (4 per wave, uniform -> vmcnt counting is wave-uniform). Linear LDS
  // dest (global_load_lds constraint); swizzle lives in the W*t layout.
  auto stage = [&](int tn) {
    int sl = tn % 3;
    const char* s2 = (const char*)W2a + tn * 8192;
    const char* s3 = (const char*)W3a + tn * 7168;
    char* d2 = (char*)&bufW2[sl][0][0];
    char* d3 = (char*)&bufW3[sl][0][0];
#pragma unroll
    for (int r = 0; r < 4; ++r) {
      int id = wv + r * 4;
      const char* src;
      char* dst;
      if (id < 8)       { src = s2 + id * 1024 + lane * 16;       dst = d2 + id * 1024; }
      else if (id < 15) { src = s3 + (id - 8) * 1024 + lane * 16; dst = d3 + (id - 8) * 1024; }
      else              { src = s3 + 6 * 1024 + lane * 16;        dst = (char*)&dummyLds[0]; }
      __builtin_amdgcn_global_load_lds(
          (const __attribute__((address_space(1))) unsigned int*)src,
          (__attribute__((address_space(3))) unsigned int*)dst, 16, 0, 0);
    }
  };

  stage(0);   // prologue stage overlaps the L1 phase below

  // zero this wave's h1s pad cols 112..127 (read as A-frag k=96..127)
  for (int i = lane; i < 16 * 16; i += 64)
    h1s[wv][i >> 4][112 + (i & 15)] = (bf16)0.0f;

  // ---- L1: 6(+bias)->100, per m-tile, A2 frags kept in registers ----
  bf16x8 A2[2][4];
#pragma unroll
  for (int mi = 0; mi < 2; ++mi) {
    bf16x8 aAtt;
#pragma unroll
    for (int i = 0; i < 8; ++i) aAtt[i] = (bf16)0.0f;
    int slot = start + wv * 32 + mi * 16 + c;
    if (q == 0 && slot < count)
      aAtt = *(const bf16x8*)(attC + ((size_t)a * B_ROWS + slot) * 8);
#pragma unroll
    for (int nt = 0; nt < 7; ++nt) {
      bf16x8 bw = *(const bf16x8*)(W1a + (nt * 16 + c) * 32 + q * 8);
      f32x4 C = {0.f, 0.f, 0.f, 0.f};
      C = MFMA16(aAtt, bw, C);
      int n = nt * 16 + c;
#pragma unroll
      for (int rg = 0; rg < 4; ++rg) {
        float v = (n < 100) ? (C[rg] > 0.f ? C[rg] : 0.f)
                            : (n == 100 ? 1.0f : 0.0f);
        h1s[wv][q * 4 + rg][n] = (bf16)v;
      }
    }
    ORDER();
#pragma unroll
    for (int tt = 0; tt < 4; ++tt)
      A2[mi][tt] = *(const bf16x8*)&h1s[wv][c][tt * 32 + q * 8];
    ORDER();   // before next mi overwrites h1s
  }

  f32x4 C3[2][7];
#pragma unroll
  for (int mi = 0; mi < 2; ++mi)
#pragma unroll
    for (int i = 0; i < 7; ++i) C3[mi][i] = (f32x4){0.f, 0.f, 0.f, 0.f};

  // ---- L2+L3 fused, 13 iterations, triple-buffered counted-vmcnt ----
#pragma unroll 1
  for (int t = 0; t < 13; ++t) {
    if (t < 12) {
      stage(t + 1);                       // 4 loads/wave into slot (t+1)%3
      asm volatile("s_waitcnt vmcnt(4)" ::: "memory");   // stage(t) landed
    } else {
      asm volatile("s_waitcnt vmcnt(0)" ::: "memory");   // final chunk landed
    }
    __builtin_amdgcn_s_barrier();         // all waves' stage(t) landed
    __builtin_amdgcn_sched_barrier(0);    // nothing crosses the barrier

    int sl = t % 3;
    const bf16* cw2 = &bufW2[sl][0][0];
    const bf16* cw3 = &bufW3[sl][0][0];
    // fragment reads from swizzled LDS images (8 lanes/bank = b128-optimal)
    bf16x8 w3f[7];
#pragma unroll
    for (int nt3 = 0; nt3 < 7; ++nt3)
      w3f[nt3] = *(const bf16x8*)(cw3 + (nt3 * 16 + c) * 32 + ((q ^ cx3) << 3));
    bf16x8 b2f[2][4];
#pragma unroll
    for (int half = 0; half < 2; ++half)
#pragma unroll
      for (int tt = 0; tt < 4; ++tt)
        b2f[half][tt] = *(const bf16x8*)(cw2 + (half * 16 + c) * 128 +
                                         ((((tt << 2) + q) ^ cx7) << 3));

    // L2: h2 chunk (32 cols) for both m-tiles
#pragma unroll
    for (int mi = 0; mi < 2; ++mi)
#pragma unroll
      for (int half = 0; half < 2; ++half) {
        f32x4 C = {0.f, 0.f, 0.f, 0.f};
#pragma unroll
        for (int tt = 0; tt < 4; ++tt)
          C = MFMA16(A2[mi][tt], b2f[half][tt], C);
#pragma unroll
        for (int rg = 0; rg < 4; ++rg) {
          float v = C[rg] > 0.f ? C[rg] : 0.f;
          tr[wv][mi][q * 4 + rg][half * 16 + c] = (bf16)v;
        }
      }
    ORDER();
    bf16x8 A3a = *(const bf16x8*)&tr[wv][0][c][q * 8];
    bf16x8 A3b = *(const bf16x8*)&tr[wv][1][c][q * 8];
#pragma unroll
    for (int nt3 = 0; nt3 < 7; ++nt3) {
      C3[0][nt3] = MFMA16(A3a, w3f[nt3], C3[0][nt3]);
      C3[1][nt3] = MFMA16(A3b, w3f[nt3], C3[1][nt3]);
    }
    ORDER();
    // own DS reads complete before signaling the next barrier (WAR gate)
    asm volatile("s_waitcnt lgkmcnt(0)" ::: "memory");
    __builtin_amdgcn_sched_barrier(0);
  }

  // ---- L4: 100(+bias)->6 + MSE, per m-tile (h1s serial reuse) ----
  bf16x8 b4f[4];
#pragma unroll
  for (int tt = 0; tt < 4; ++tt)
    b4f[tt] = *(const bf16x8*)(W4a + c * 128 + tt * 32 + q * 8);
  float sq = 0.f;
#pragma unroll
  for (int mi = 0; mi < 2; ++mi) {
#pragma unroll
    for (int nt3 = 0; nt3 < 7; ++nt3) {
      int n = nt3 * 16 + c;
#pragma unroll
      for (int rg = 0; rg < 4; ++rg) {
        float v = (n < 100) ? (C3[mi][nt3][rg] > 0.f ? C3[mi][nt3][rg] : 0.f)
                            : (n == 100 ? 1.0f : 0.0f);
        h1s[wv][q * 4 + rg][n] = (bf16)v;
      }
    }
    ORDER();
    f32x4 C4 = {0.f, 0.f, 0.f, 0.f};
#pragma unroll
    for (int tt = 0; tt < 4; ++tt) {
      bf16x8 A4 = *(const bf16x8*)&h1s[wv][c][tt * 32 + q * 8];
      C4 = MFMA16(A4, b4f[tt], C4);
    }
    ORDER();   // before next mi overwrites h1s
    if (c < 6) {
#pragma unroll
      for (int rg = 0; rg < 4; ++rg) {
        int slot = start + wv * 32 + mi * 16 + q * 4 + rg;
        if (slot < count) {
          float d = deltaC[((size_t)a * B_ROWS + slot) * 6 + c];
          float e = C4[rg] - d;
          sq += e * e;
        }
      }
    }
  }
#pragma unroll
  for (int off = 32; off; off >>= 1) sq += __shfl_xor(sq, off);
  if (lane == 0) s_part[wv] = sq;
  __syncthreads();
  if (threadIdx.x == 0)
    partial[b] = s_part[0] + s_part[1] + s_part[2] + s_part[3];
}

// One-block tree reduction over per-block partials.
__global__ __launch_bounds__(256) void k_final(
    const float* __restrict__ partial, float* __restrict__ out)
{
  __shared__ float s[4];
  int t = threadIdx.x, lane = t & 63, wv = t >> 6;
  float sum = 0.f;
  for (int i = t; i < MLP_GRID; i += 256) sum += partial[i];
#pragma unroll
  for (int off = 32; off; off >>= 1) sum += __shfl_xor(sum, off);
  if (lane == 0) s[wv] = sum;
  __syncthreads();
  if (t == 0) {
    double tot = (double)s[0] + s[1] + s[2] + s[3];
    out[0] = (float)(tot / (double)(B_ROWS * 6));
  }
}

extern "C" void kernel_launch(void* const* d_in, const int* in_sizes, int n_in,
                              void* d_out, int out_size, void* d_ws, size_t ws_size,
                              hipStream_t stream)
{
  const float* x  = (const float*)d_in[0];
  const float* xn = (const float*)d_in[1];
  const int*  act = (const int*)d_in[2];
  const float* W1 = (const float*)d_in[3];
  const float* b1 = (const float*)d_in[4];
  const float* W2 = (const float*)d_in[5];
  const float* b2 = (const float*)d_in[6];
  const float* W3 = (const float*)d_in[7];
  const float* b3 = (const float*)d_in[8];
  const float* W4 = (const float*)d_in[9];
  const float* b4 = (const float*)d_in[10];

  char* ws = (char*)d_ws;
  bf16*   W1t    = (bf16*)(ws + OFF_W1T);
  bf16*   W2t    = (bf16*)(ws + OFF_W2T);
  bf16*   W3t    = (bf16*)(ws + OFF_W3T);
  bf16*   W4t    = (bf16*)(ws + OFF_W4T);
  int*    cnt    = (int*)(ws + OFF_CNT);
  int*    ptrArr = (int*)(ws + OFF_PTR);
  bf16*   attC   = (bf16*)(ws + OFF_ATTC);
  float*  deltaC = (float*)(ws + OFF_DELTA);
  float*  part   = (float*)(ws + OFF_PART);

  k_prep<<<dim3(WPREP_BLOCKS + SCAN_BLOCKS), dim3(256), 0, stream>>>(
      W1, b1, W2, b2, W3, b3, W4, b4, x, W1t, W2t, W3t, W4t, cnt, ptrArr);
  k_gather2<<<dim3(B_ROWS / 256), dim3(256), 0, stream>>>(x, xn, act, ptrArr,
                                                          attC, deltaC, cnt);
  k_mlp<<<dim3(MLP_GRID), dim3(256), 0, stream>>>(W1t, W2t, W3t, W4t,
                                                  attC, deltaC, cnt, part);
  k_final<<<dim3(1), dim3(256), 0, stream>>>(part, (float*)d_out);
}

// Round 5
// 268.110 us; speedup vs baseline: 1.2119x; 1.0172x over previous
//
#include <hip/hip_runtime.h>
#include <hip/hip_bf16.h>

#define B_ROWS 65536
#define XD 362

typedef __bf16 bf16;
typedef __attribute__((ext_vector_type(8))) __bf16 bf16x8;
typedef __attribute__((ext_vector_type(4))) __bf16 bf16x4;
typedef __attribute__((ext_vector_type(4))) float f32x4;
typedef __attribute__((ext_vector_type(2))) float f32x2;

#define MFMA16(A, Bf, C) __builtin_amdgcn_mfma_f32_16x16x32_bf16(A, Bf, C, 0, 0, 0)
#define ORDER() __builtin_amdgcn_sched_barrier(0x7F)

// ---- workspace layout (bytes) ----
#define OFF_W1T   0u          // [3][112][32] bf16
#define OFF_W2T   21504u      // [3][416][128] bf16, granule-swizzled
#define OFF_W3T   340992u     // [3][13][112][32] bf16, granule-swizzled
#define OFF_W4T   620544u     // [3][16][128] bf16
#define OFF_CNT   632832u     // int[3]
#define OFF_PTR   633088u     // int[65536]
#define OFF_ATTC  895232u     // [3][65536][8] bf16
#define OFF_DELTA 4040960u    // [3][65536][6] f32
#define OFF_PART  8759552u    // float[MLP_GRID] per-block partials

#define MLP_GRID 520
#define WPREP_BLOCKS 624
#define SCAN_BLOCKS 2896      // 2896*256*8 float4 == 65536*362/4 exactly

// W2t swizzle: [a][n][g*8+e] stores W2^T[n][k=(g^(n&7))*8+e]  (g 0..15)
// W3t swizzle: [a][t][n][g*8+e] stores W3^T[n][k=t*32+(g^(n&3))*8+e] (g 0..3)

__global__ __launch_bounds__(256) void k_prep(
    const float* __restrict__ W1, const float* __restrict__ b1,
    const float* __restrict__ W2, const float* __restrict__ b2,
    const float* __restrict__ W3, const float* __restrict__ b3,
    const float* __restrict__ W4, const float* __restrict__ b4,
    const float* __restrict__ x,
    bf16* __restrict__ W1t, bf16* __restrict__ W2t,
    bf16* __restrict__ W3t, bf16* __restrict__ W4t,
    int* __restrict__ cnt, int* __restrict__ ptrArr)
{
  int bx = blockIdx.x;
  if (bx >= WPREP_BLOCKS) {
    int gid = (bx - WPREP_BLOCKS) * 256 + threadIdx.x;
    const float4* x4 = (const float4*)x;
#pragma unroll
    for (int u = 0; u < 8; ++u) {
      int i = gid + u * (SCAN_BLOCKS * 256);
      float4 v = x4[i];
      if (v.x == 10.0f || v.y == 10.0f || v.z == 10.0f || v.w == 10.0f) {
        int flat = i * 4;
        if (v.x == 10.0f) ptrArr[(flat    ) / XD] = (flat    ) % XD;
        if (v.y == 10.0f) ptrArr[(flat + 1) / XD] = (flat + 1) % XD;
        if (v.z == 10.0f) ptrArr[(flat + 2) / XD] = (flat + 2) % XD;
        if (v.w == 10.0f) ptrArr[(flat + 3) / XD] = (flat + 3) % XD;
      }
    }
    return;
  }
  int i = bx * 256 + threadIdx.x;
  if (i == 0) { cnt[0] = 0; cnt[1] = 0; cnt[2] = 0; }
  if (i < 3*416*128) {               // W2t [n=416][128], granule-swizzled
    int e = i & 7; int g = (i >> 3) & 15;
    int rn = i >> 7; int n = rn % 416; int a = rn / 416;
    int k = ((g ^ (n & 7)) << 3) | e;
    float v = 0.f;
    if (n < 400) {
      if (k < 100) v = W2[(a*100 + k)*400 + n];
      else if (k == 100) v = b2[a*400 + n];
    } else if (n == 400) {
      v = (k == 100) ? 1.0f : 0.0f;  // bias-marker row
    }
    W2t[i] = (bf16)v;
  }
  if (i < 3*13*112*32) {             // W3t [13][n=112][32], granule-swizzled
    int e = i & 7; int g = (i >> 3) & 3;
    int n = (i >> 5) % 112; int tc = ((i >> 5) / 112) % 13; int a = i / (13*112*32);
    int k = tc * 32 + ((g ^ (n & 3)) << 3) + e;
    float v = 0.f;
    if (n < 100) {
      if (k < 400) v = W3[(a*400 + k)*100 + n];
      else if (k == 400) v = b3[a*100 + n];
    }
    W3t[i] = (bf16)v;
  }
  if (i < 3*112*32) {                // W1t [n=112][k=32]
    int k = i & 31; int rn = i >> 5; int n = rn % 112; int a = rn / 112;
    float v = 0.f;
    if (n < 100) {
      if (k < 6) v = W1[(a*6 + k)*100 + n];
      else if (k == 6) v = b1[a*100 + n];
    }
    W1t[i] = (bf16)v;
  }
  if (i < 3*16*128) {                // W4t [n=16][k=128]
    int k = i & 127; int rn = i >> 7; int n = rn & 15; int a = rn >> 4;
    float v = 0.f;
    if (n < 6) {
      if (k < 100) v = W4[(a*100 + k)*6 + n];
      else if (k == 100) v = b4[a*6 + n];
    }
    W4t[i] = (bf16)v;
  }
}

__global__ __launch_bounds__(256) void k_gather2(
    const float* __restrict__ x, const float* __restrict__ xn,
    const int* __restrict__ act, const int* __restrict__ ptrArr,
    bf16* __restrict__ attC, float* __restrict__ deltaC, int* __restrict__ cnt)
{
  int row = blockIdx.x * 256 + threadIdx.x;
  int lane = threadIdx.x & 63;
  int p = ptrArr[row];
  if (p < 20 || p > 342) p = 20;
  const float* xr = x  + (size_t)row * XD;
  const float* nr = xn + (size_t)row * XD;
  int cells[6] = {0, p, p - 19, p + 19, p - 1, p + 1};
  float av[6], dv[6];
#pragma unroll
  for (int i = 0; i < 6; ++i) {
    av[i] = xr[cells[i]];
    dv[i] = nr[cells[i]] - av[i];
  }
  int a = act[row];
  unsigned long long m0 = __ballot(a == 0);
  unsigned long long m1 = __ballot(a == 1);
  unsigned long long m2 = __ballot(a == 2);
  int b0 = 0, b1 = 0, b2 = 0;
  if (lane == 0) {
    b0 = atomicAdd(&cnt[0], (int)__popcll(m0));
    b1 = atomicAdd(&cnt[1], (int)__popcll(m1));
    b2 = atomicAdd(&cnt[2], (int)__popcll(m2));
  }
  b0 = __shfl(b0, 0); b1 = __shfl(b1, 0); b2 = __shfl(b2, 0);
  unsigned long long lt = (1ull << lane) - 1ull;
  unsigned long long ma = (a == 0) ? m0 : (a == 1) ? m1 : m2;
  int base            = (a == 0) ? b0 : (a == 1) ? b1 : b2;
  int slot = base + (int)__popcll(ma & lt);
  size_t rb = (size_t)a * B_ROWS + slot;
  bf16x8 av8;
#pragma unroll
  for (int i = 0; i < 6; ++i) av8[i] = (bf16)av[i];
  av8[6] = (bf16)1.0f;
  av8[7] = (bf16)0.0f;
  *(bf16x8*)(attC + rb * 8) = av8;
  f32x2 d01 = {dv[0], dv[1]}, d23 = {dv[2], dv[3]}, d45 = {dv[4], dv[5]};
  *(f32x2*)(deltaC + rb * 6)     = d01;
  *(f32x2*)(deltaC + rb * 6 + 2) = d23;
  *(f32x2*)(deltaC + rb * 6 + 4) = d45;
}

// 128-row tiles, 4 waves x 32 rows. Loop restructured to break the per-iter
// serial chain (the measured ~33us floor):
//  * swapped MFMA operands (weights as A-operand): L2/L3 output is [n][batch],
//    so the h2/h3 transpose is ONE packed ds_write_b64 per 16x16 fragment
//    (was 16 scalar b16 writes).
//  * L3 skewed one iteration behind L2: its LDS reads (h2ch + W3 frags)
//    consume data >=1 iteration old -> no intra-iter LDS round-trip stall.
//  * weight LDS slots reduced to 2 (reads happen the iter after staging);
//    prefetch depth 1, vmcnt(0) at iter top is effectively free.
//  * setprio(1) around the MFMA cluster (T5).
__global__ __launch_bounds__(256, 2) void k_mlp(
    const bf16* __restrict__ W1t, const bf16* __restrict__ W2t,
    const bf16* __restrict__ W3t, const bf16* __restrict__ W4t,
    const bf16* __restrict__ attC, const float* __restrict__ deltaC,
    const int* __restrict__ cnt, float* __restrict__ partial)
{
  int c0 = cnt[0], c1 = cnt[1], c2 = cnt[2];
  int T0 = (c0 + 127) >> 7, T1 = (c1 + 127) >> 7, T2 = (c2 + 127) >> 7;
  int b = blockIdx.x;
  int a, tile, count;
  if (b < T0)           { a = 0; tile = b;            count = c0; }
  else if (b < T0 + T1) { a = 1; tile = b - T0;       count = c1; }
  else if (b < T0 + T1 + T2) { a = 2; tile = b - T0 - T1; count = c2; }
  else { if (threadIdx.x == 0) partial[b] = 0.f; return; }
  int start = tile << 7;

  __shared__ __align__(16) bf16 bufW2[2][32][128];    // 2 x 8 KB W2 chunk
  __shared__ __align__(16) bf16 bufW3[2][112][32];    // 2 x 7 KB W3 chunk
  __shared__ __align__(16) bf16 dummyLds[512];        // stage filler
  __shared__ __align__(16) bf16 h1s[4][16][136];      // per-wave [batch][k] scratch
  __shared__ __align__(16) bf16 h2ch[4][2][2][16][40];// per-wave,dbuf,mi [batch][k2c]
  __shared__ float s_part[4];
  int wv = threadIdx.x >> 6, lane = threadIdx.x & 63;
  int q = lane >> 4, c = lane & 15;
  int cx7 = c & 7, cx3 = c & 3;

  const bf16* W1a = W1t + a * 112 * 32;
  const bf16* W2a = W2t + a * 416 * 128;
  const bf16* W3a = W3t + a * 13 * 112 * 32;
  const bf16* W4a = W4t + a * 16 * 128;

  // cooperative stage of chunk tn into slot tn&1: 16 x 1KB wave-loads
  // (4/wave). Linear LDS dest; swizzle lives in the W*t global layout.
  auto stage = [&](int tn) {
    int sl = tn & 1;
    const char* s2 = (const char*)W2a + tn * 8192;
    const char* s3 = (const char*)W3a + tn * 7168;
    char* d2 = (char*)&bufW2[sl][0][0];
    char* d3 = (char*)&bufW3[sl][0][0];
#pragma unroll
    for (int r = 0; r < 4; ++r) {
      int id = wv + r * 4;
      const char* src;
      char* dst;
      if (id < 8)       { src = s2 + id * 1024 + lane * 16;       dst = d2 + id * 1024; }
      else if (id < 15) { src = s3 + (id - 8) * 1024 + lane * 16; dst = d3 + (id - 8) * 1024; }
      else              { src = s3 + 6 * 1024 + lane * 16;        dst = (char*)&dummyLds[0]; }
      __builtin_amdgcn_global_load_lds(
          (const __attribute__((address_space(1))) unsigned int*)src,
          (__attribute__((address_space(3))) unsigned int*)dst, 16, 0, 0);
    }
  };

  stage(0);   // overlaps the L1 phase

  // zero h1s pad cols 112..127 (read as A-frag k=96..127 in L1/L4)
  for (int i = lane; i < 16 * 16; i += 64)
    h1s[wv][i >> 4][112 + (i & 15)] = (bf16)0.0f;

  // ---- L1: 6(+bias)->100, per m-tile, A2 frags kept in registers ----
  bf16x8 A2[2][4];
#pragma unroll
  for (int mi = 0; mi < 2; ++mi) {
    bf16x8 aAtt;
#pragma unroll
    for (int i = 0; i < 8; ++i) aAtt[i] = (bf16)0.0f;
    int slot = start + wv * 32 + mi * 16 + c;
    if (q == 0 && slot < count)
      aAtt = *(const bf16x8*)(attC + ((size_t)a * B_ROWS + slot) * 8);
#pragma unroll
    for (int nt = 0; nt < 7; ++nt) {
      bf16x8 bw = *(const bf16x8*)(W1a + (nt * 16 + c) * 32 + q * 8);
      f32x4 C = {0.f, 0.f, 0.f, 0.f};
      C = MFMA16(aAtt, bw, C);
      int n = nt * 16 + c;
#pragma unroll
      for (int rg = 0; rg < 4; ++rg) {
        float v = (n < 100) ? (C[rg] > 0.f ? C[rg] : 0.f)
                            : (n == 100 ? 1.0f : 0.0f);
        h1s[wv][q * 4 + rg][n] = (bf16)v;
      }
    }
    ORDER();
#pragma unroll
    for (int tt = 0; tt < 4; ++tt)
      A2[mi][tt] = *(const bf16x8*)&h1s[wv][c][tt * 32 + q * 8];
    ORDER();   // before next mi overwrites h1s
  }

  f32x4 C3[2][7];   // lane holds out3[n3=nt3*16+q*4+rg][batch=c]
#pragma unroll
  for (int mi = 0; mi < 2; ++mi)
#pragma unroll
    for (int i = 0; i < 7; ++i) C3[mi][i] = (f32x4){0.f, 0.f, 0.f, 0.f};

  bf16x8 w3fP[7];

  // ---- iter 0 (peeled): L2(0) only ----
  asm volatile("s_waitcnt vmcnt(0)" ::: "memory");   // own stage(0) landed
  __builtin_amdgcn_s_barrier();                      // all waves' stage(0) landed
  __builtin_amdgcn_sched_barrier(0);
  stage(1);
  {
    const bf16* cw2 = &bufW2[0][0][0];
    const bf16* cw3 = &bufW3[0][0][0];
#pragma unroll
    for (int nt3 = 0; nt3 < 7; ++nt3)
      w3fP[nt3] = *(const bf16x8*)(cw3 + (nt3 * 16 + c) * 32 + ((q ^ cx3) << 3));
    bf16x8 b2f[2][4];
#pragma unroll
    for (int half = 0; half < 2; ++half)
#pragma unroll
      for (int tt = 0; tt < 4; ++tt)
        b2f[half][tt] = *(const bf16x8*)(cw2 + (half * 16 + c) * 128 +
                                         ((((tt << 2) + q) ^ cx7) << 3));
    __builtin_amdgcn_sched_barrier(0);
    __builtin_amdgcn_s_setprio(1);
#pragma unroll
    for (int mi = 0; mi < 2; ++mi)
#pragma unroll
      for (int half = 0; half < 2; ++half) {
        f32x4 C = {0.f, 0.f, 0.f, 0.f};
#pragma unroll
        for (int tt = 0; tt < 4; ++tt)
          C = MFMA16(b2f[half][tt], A2[mi][tt], C);
        bf16x4 pk;
#pragma unroll
        for (int rg = 0; rg < 4; ++rg)
          pk[rg] = (bf16)(C[rg] > 0.f ? C[rg] : 0.f);
        *(bf16x4*)&h2ch[wv][0][mi][c][half * 16 + q * 4] = pk;
      }
    __builtin_amdgcn_s_setprio(0);
    asm volatile("s_waitcnt lgkmcnt(0)" ::: "memory");
    __builtin_amdgcn_sched_barrier(0);
  }

  // ---- iters 1..12: L2(t) + L3(t-1), skewed ----
#pragma unroll 1
  for (int t = 1; t < 13; ++t) {
    asm volatile("s_waitcnt vmcnt(0)" ::: "memory");  // own stage(t) landed
    __builtin_amdgcn_s_barrier();                     // all waves' stage(t) landed
    __builtin_amdgcn_sched_barrier(0);
    if (t < 12) stage(t + 1);
    const bf16* cw2 = &bufW2[t & 1][0][0];
    const bf16* cw3 = &bufW3[t & 1][0][0];
    // L3(t-1) A-operand: h2 chunk written LAST iteration (no fresh dependency)
    bf16x8 A3[2];
#pragma unroll
    for (int mi = 0; mi < 2; ++mi)
      A3[mi] = *(const bf16x8*)&h2ch[wv][(t - 1) & 1][mi][c][q * 8];
    bf16x8 w3fN[7];
#pragma unroll
    for (int nt3 = 0; nt3 < 7; ++nt3)
      w3fN[nt3] = *(const bf16x8*)(cw3 + (nt3 * 16 + c) * 32 + ((q ^ cx3) << 3));
    bf16x8 b2f[2][4];
#pragma unroll
    for (int half = 0; half < 2; ++half)
#pragma unroll
      for (int tt = 0; tt < 4; ++tt)
        b2f[half][tt] = *(const bf16x8*)(cw2 + (half * 16 + c) * 128 +
                                         ((((tt << 2) + q) ^ cx7) << 3));
    __builtin_amdgcn_sched_barrier(0);
    __builtin_amdgcn_s_setprio(1);
    // L3(t-1): weights (w3fP) register-carried from last iteration
#pragma unroll
    for (int nt3 = 0; nt3 < 7; ++nt3) {
      C3[0][nt3] = MFMA16(w3fP[nt3], A3[0], C3[0][nt3]);
      C3[1][nt3] = MFMA16(w3fP[nt3], A3[1], C3[1][nt3]);
    }
    // L2(t): write h2 chunk packed (one b64 per fragment)
#pragma unroll
    for (int mi = 0; mi < 2; ++mi)
#pragma unroll
      for (int half = 0; half < 2; ++half) {
        f32x4 C = {0.f, 0.f, 0.f, 0.f};
#pragma unroll
        for (int tt = 0; tt < 4; ++tt)
          C = MFMA16(b2f[half][tt], A2[mi][tt], C);
        bf16x4 pk;
#pragma unroll
        for (int rg = 0; rg < 4; ++rg)
          pk[rg] = (bf16)(C[rg] > 0.f ? C[rg] : 0.f);
        *(bf16x4*)&h2ch[wv][t & 1][mi][c][half * 16 + q * 4] = pk;
      }
    __builtin_amdgcn_s_setprio(0);
#pragma unroll
    for (int nt3 = 0; nt3 < 7; ++nt3) w3fP[nt3] = w3fN[nt3];
    // own DS ops complete before signaling next barrier (weight-slot WAR gate)
    asm volatile("s_waitcnt lgkmcnt(0)" ::: "memory");
    __builtin_amdgcn_sched_barrier(0);
  }

  // ---- epilogue: L3(12) (per-wave data, no barrier needed) ----
  {
    bf16x8 A3[2];
#pragma unroll
    for (int mi = 0; mi < 2; ++mi)
      A3[mi] = *(const bf16x8*)&h2ch[wv][0][mi][c][q * 8];   // 12&1 == 0
#pragma unroll
    for (int nt3 = 0; nt3 < 7; ++nt3) {
      C3[0][nt3] = MFMA16(w3fP[nt3], A3[0], C3[0][nt3]);
      C3[1][nt3] = MFMA16(w3fP[nt3], A3[1], C3[1][nt3]);
    }
  }

  // ---- L4: 100(+bias)->6 + MSE. C3 layout: n3=nt3*16+q*4+rg, batch=c ->
  // h3 natural-layout b64 writes into h1s[batch][k3]; A4 b128 reads as before.
  bf16x8 b4f[4];
#pragma unroll
  for (int tt = 0; tt < 4; ++tt)
    b4f[tt] = *(const bf16x8*)(W4a + c * 128 + tt * 32 + q * 8);
  float sq = 0.f;
#pragma unroll
  for (int mi = 0; mi < 2; ++mi) {
#pragma unroll
    for (int nt3 = 0; nt3 < 7; ++nt3) {
      bf16x4 pk;
#pragma unroll
      for (int rg = 0; rg < 4; ++rg) {
        int k3 = nt3 * 16 + q * 4 + rg;
        float v = (k3 < 100) ? (C3[mi][nt3][rg] > 0.f ? C3[mi][nt3][rg] : 0.f)
                             : (k3 == 100 ? 1.0f : 0.0f);
        pk[rg] = (bf16)v;
      }
      *(bf16x4*)&h1s[wv][c][nt3 * 16 + q * 4] = pk;
    }
    ORDER();
    f32x4 C4 = {0.f, 0.f, 0.f, 0.f};
#pragma unroll
    for (int tt = 0; tt < 4; ++tt) {
      bf16x8 A4 = *(const bf16x8*)&h1s[wv][c][tt * 32 + q * 8];
      C4 = MFMA16(A4, b4f[tt], C4);
    }
    ORDER();   // before next mi overwrites h1s
    if (c < 6) {
#pragma unroll
      for (int rg = 0; rg < 4; ++rg) {
        int slot = start + wv * 32 + mi * 16 + q * 4 + rg;
        if (slot < count) {
          float d = deltaC[((size_t)a * B_ROWS + slot) * 6 + c];
          float e = C4[rg] - d;
          sq += e * e;
        }
      }
    }
  }
#pragma unroll
  for (int off = 32; off; off >>= 1) sq += __shfl_xor(sq, off);
  if (lane == 0) s_part[wv] = sq;
  __syncthreads();
  if (threadIdx.x == 0)
    partial[b] = s_part[0] + s_part[1] + s_part[2] + s_part[3];
}

__global__ __launch_bounds__(256) void k_final(
    const float* __restrict__ partial, float* __restrict__ out)
{
  __shared__ float s[4];
  int t = threadIdx.x, lane = t & 63, wv = t >> 6;
  float sum = 0.f;
  for (int i = t; i < MLP_GRID; i += 256) sum += partial[i];
#pragma unroll
  for (int off = 32; off; off >>= 1) sum += __shfl_xor(sum, off);
  if (lane == 0) s[wv] = sum;
  __syncthreads();
  if (t == 0) {
    double tot = (double)s[0] + s[1] + s[2] + s[3];
    out[0] = (float)(tot / (double)(B_ROWS * 6));
  }
}

extern "C" void kernel_launch(void* const* d_in, const int* in_sizes, int n_in,
                              void* d_out, int out_size, void* d_ws, size_t ws_size,
                              hipStream_t stream)
{
  const float* x  = (const float*)d_in[0];
  const float* xn = (const float*)d_in[1];
  const int*  act = (const int*)d_in[2];
  const float* W1 = (const float*)d_in[3];
  const float* b1 = (const float*)d_in[4];
  const float* W2 = (const float*)d_in[5];
  const float* b2 = (const float*)d_in[6];
  const float* W3 = (const float*)d_in[7];
  const float* b3 = (const float*)d_in[8];
  const float* W4 = (const float*)d_in[9];
  const float* b4 = (const float*)d_in[10];

  char* ws = (char*)d_ws;
  bf16*   W1t    = (bf16*)(ws + OFF_W1T);
  bf16*   W2t    = (bf16*)(ws + OFF_W2T);
  bf16*   W3t    = (bf16*)(ws + OFF_W3T);
  bf16*   W4t    = (bf16*)(ws + OFF_W4T);
  int*    cnt    = (int*)(ws + OFF_CNT);
  int*    ptrArr = (int*)(ws + OFF_PTR);
  bf16*   attC   = (bf16*)(ws + OFF_ATTC);
  float*  deltaC = (float*)(ws + OFF_DELTA);
  float*  part   = (float*)(ws + OFF_PART);

  k_prep<<<dim3(WPREP_BLOCKS + SCAN_BLOCKS), dim3(256), 0, stream>>>(
      W1, b1, W2, b2, W3, b3, W4, b4, x, W1t, W2t, W3t, W4t, cnt, ptrArr);
  k_gather2<<<dim3(B_ROWS / 256), dim3(256), 0, stream>>>(x, xn, act, ptrArr,
                                                          attC, deltaC, cnt);
  k_mlp<<<dim3(MLP_GRID), dim3(256), 0, stream>>>(W1t, W2t, W3t, W4t,
                                                  attC, deltaC, cnt, part);
  k_final<<<dim3(1), dim3(256), 0, stream>>>(part, (float*)d_out);
}